// Round 9
// baseline (171.981 us; speedup 1.0000x reference)
//
#include <hip/hip_runtime.h>
#include <math.h>

// Problem constants
#define NB 8           // batch
#define TOPN 4
#define NC 80          // classes
#define NF 1280        // features
#define HW 448         // image H=W
#define OS 14          // conv out spatial
#define NP 196         // OS*OS
#define PATCH (3*42*42)   // full 42x42x3 crop sample grid
#define ROWPATCH (3*3*42) // one output-row's input grid: 3 ch x 3 rows x 42 cols
#define WLDS (256*27)     // per-chunk filter weights staged in LDS

__device__ __forceinline__ float sigmoidf_(float x) { return 1.0f / (1.0f + expf(-x)); }

__device__ __forceinline__ double wave_reduce_f64(double v) {
#pragma unroll
  for (int off = 32; off > 0; off >>= 1) v += __shfl_down(v, off);
  return v;
}

// ---------------- K1: global conv (stride 32, pad 1, clip 0..6), row-split 14x.
// grid (5, 8, 14): x = filter chunk (256 filters), y = batch, z = output row oy.
__global__ __launch_bounds__(256) void k1_conv_global(
    const float* __restrict__ in,   // (8,3,448,448)
    const float* __restrict__ fw,   // (1280,3,3,3) flat
    const float* __restrict__ fb,   // (1280)
    float* __restrict__ ga,         // (8,196,1280)
    double* __restrict__ gfp)       // (14,8,1280) per-row partial sums
{
  __shared__ float patch[ROWPATCH];   // [c][rr][cc] : c*126 + rr*42 + cc
  __shared__ float wlds[WLDS];
  const int b = blockIdx.y, fc = blockIdx.x, oy = blockIdx.z, tid = threadIdx.x;
  for (int i = tid; i < WLDS; i += 256) wlds[i] = fw[fc * WLDS + i];
  for (int i = tid; i < ROWPATCH; i += 256) {
    int c = i / 126, rem = i % 126, rr = rem / 42, cc = rem % 42;
    int row = 32 * oy + rr - 1;
    int col = 32 * (cc / 3) + (cc % 3) - 1;
    float v = 0.0f;
    if (row >= 0 && col >= 0)
      v = in[((b * 3 + c) * HW + row) * HW + col];
    patch[i] = v;
  }
  __syncthreads();
  const int f = fc * 256 + tid;
  float w[27];
#pragma unroll
  for (int k = 0; k < 27; ++k) w[k] = wlds[tid * 27 + k];
  const float bias = fb[f];
  double sum = 0.0;
#pragma unroll 7
  for (int ox = 0; ox < OS; ++ox) {
    float acc = bias;
#pragma unroll
    for (int c = 0; c < 3; ++c)
#pragma unroll
      for (int ky = 0; ky < 3; ++ky)
#pragma unroll
        for (int kx = 0; kx < 3; ++kx)
          acc += patch[c * 126 + ky * 42 + ox * 3 + kx] * w[c * 9 + ky * 3 + kx];
    acc = fminf(fmaxf(acc, 0.0f), 6.0f);
    ga[((size_t)b * NP + oy * OS + ox) * NF + f] = acc;
    sum += (double)acc;
  }
  gfp[((size_t)oy * NB + b) * NF + f] = sum;
}

// ---------------- K2: gs = sigmoid(1x1 conv on gf) + top-4, one 1024-thread block per batch.
__global__ __launch_bounds__(1024) void k2_gs_topk(
    const double* __restrict__ gfp, // (14,8,1280)
    const float* __restrict__ cw,   // (80,1280)
    const float* __restrict__ cb,   // (80)
    float* __restrict__ gs_out,     // d_out (8,80)
    int* __restrict__ topi)         // (8,4)
{
  __shared__ float gfs[NF];
  __shared__ float gsv[NC];
  const int b = blockIdx.x, tid = threadIdx.x;
  for (int i = tid; i < NF; i += 1024) {
    double s = 0.0;
#pragma unroll
    for (int z = 0; z < OS; ++z) s += gfp[((size_t)z * NB + b) * NF + i];
    gfs[i] = (float)(s / 196.0);
  }
  __syncthreads();
  const int wid = tid >> 6, lane = tid & 63;
  for (int j = 0; j < 5; ++j) {
    const int cls = wid * 5 + j;
    const float* w = cw + (size_t)cls * NF;
    double acc = 0.0;
#pragma unroll
    for (int k = 0; k < NF / 64; ++k) {
      int f = k * 64 + lane;
      acc += (double)w[f] * (double)gfs[f];
    }
    acc = wave_reduce_f64(acc);
    if (lane == 0) {
      float s = sigmoidf_((float)(acc + (double)cb[cls]));
      gsv[cls] = s;
      gs_out[b * NC + cls] = s;
    }
  }
  __syncthreads();
  if (wid == 0) {
    float v0 = gsv[lane];
    float v1 = (lane < NC - 64) ? gsv[64 + lane] : -1e30f;
    const int i0 = lane, i1 = 64 + lane;
#pragma unroll
    for (int t = 0; t < TOPN; ++t) {
      float bv; int bi;
      if (v1 > v0) { bv = v1; bi = i1; } else { bv = v0; bi = i0; }
#pragma unroll
      for (int off = 1; off < 64; off <<= 1) {
        float ov = __shfl_xor(bv, off);
        int oi = __shfl_xor(bi, off);
        if (ov > bv || (ov == bv && oi < bi)) { bv = ov; bi = oi; }
      }
      if (lane == 0) topi[b * TOPN + t] = bi;
      if (bi == i0) v0 = -1e30f;
      if (bi == i1) v1 = -1e30f;
    }
  }
}

// ---------------- K3 (fused): per bt, 1024 threads: cam dots -> segment-max scores
//                  -> bounds -> bilinear crop-stage -> zero lfa accumulator.
__global__ __launch_bounds__(1024) void k3_cam_bounds_stage(
    const float* __restrict__ ga,   // (8,196,1280)
    const float* __restrict__ cw,
    const float* __restrict__ cb,
    const int* __restrict__ topi,
    const float* __restrict__ in,   // (8,3,448,448)
    float* __restrict__ patchg,     // (32,5292)
    double* __restrict__ lfa)       // (32,1280) accumulator, zeroed here
{
  __shared__ float clsw[NF];
  __shared__ float cam[NP];
  __shared__ float wsS[HW];
  __shared__ float hsS[HW];
  __shared__ int jlo[OS], jhi[OS];
  __shared__ int shb[4];            // y1,y2,x1,x2
  const int bt = blockIdx.x, tid = threadIdx.x;
  const int wid = tid >> 6, lane = tid & 63;
  const int b = bt >> 2;
  const int cls = topi[bt];
  const float SC = 13.0f / 447.0f;

  if (tid < OS) { jlo[tid] = 1 << 30; jhi[tid] = -1; }
  for (int i = tid; i < NF; i += 1024) clsw[i] = cw[(size_t)cls * NF + i];
  // zero the k4 accumulation buffer (runs before k4 in stream order)
  for (int i = tid; i < NF; i += 1024) lfa[(size_t)bt * NF + i] = 0.0;
  __syncthreads();

  // phase A: cam — 196 dots over 16 waves, 4 positions in flight per wave
  const double bias = (double)cb[cls];
  for (int p0 = wid; p0 < NP; p0 += 64) {
    double a[4] = {0.0, 0.0, 0.0, 0.0};
    const float* g[4];
    int pv[4];
#pragma unroll
    for (int s = 0; s < 4; ++s) {
      int p = p0 + 16 * s;
      pv[s] = (p < NP) ? p : -1;
      g[s] = ga + ((size_t)b * NP + ((p < NP) ? p : 0)) * NF;
    }
#pragma unroll
    for (int k = 0; k < NF / 64; ++k) {
      const int f = k * 64 + lane;
      const double wv = (double)clsw[f];
#pragma unroll
      for (int s = 0; s < 4; ++s) a[s] += (double)g[s][f] * wv;
    }
#pragma unroll
    for (int s = 0; s < 4; ++s) {
      a[s] = wave_reduce_f64(a[s]);
      if (lane == 0 && pv[s] >= 0) cam[pv[s]] = sigmoidf_((float)(a[s] + bias));
    }
  }
  __syncthreads();

  // per-segment extreme sample indices (identical floor/clamp math as reference sampling)
  for (int j = tid; j < HW; j += 1024) {
    float yp = (float)j * SC;
    int y0 = (int)floorf(yp); if (y0 > 13) y0 = 13;
    atomicMin(&jlo[y0], j);
    atomicMax(&jhi[y0], j);
  }
  __syncthreads();

  // phase B: per output column/row, piecewise-linear segment max (2 evals/segment)
  for (int x = tid; x < HW; x += 1024) {
    float xp = (float)x * SC;
    int x0 = (int)floorf(xp); if (x0 > 13) x0 = 13;
    float wx = xp - (float)x0;
    int x1i = min(x0 + 1, 13);
    {
      float cv[OS];
#pragma unroll
      for (int r = 0; r < OS; ++r)
        cv[r] = cam[r * OS + x0] * (1.0f - wx) + cam[r * OS + x1i] * wx;
      float m = -1e30f;
#pragma unroll
      for (int r = 0; r < OS; ++r) {
        int jl = jlo[r], jh = jhi[r];
        if (jl <= jh) {
          const int rn = (r + 1 < OS) ? r + 1 : OS - 1;
          float yp1 = (float)jl * SC; float wy1 = yp1 - (float)r;
          float yp2 = (float)jh * SC; float wy2 = yp2 - (float)r;
          float v1 = cv[r] * (1.0f - wy1) + cv[rn] * wy1;
          float v2 = cv[r] * (1.0f - wy2) + cv[rn] * wy2;
          m = fmaxf(m, fmaxf(v1, v2));
        }
      }
      wsS[x] = m;
    }
    {
      float cv[OS];
#pragma unroll
      for (int c = 0; c < OS; ++c)
        cv[c] = cam[x0 * OS + c] * (1.0f - wx) + cam[x1i * OS + c] * wx;
      float m = -1e30f;
#pragma unroll
      for (int r = 0; r < OS; ++r) {
        int jl = jlo[r], jh = jhi[r];
        if (jl <= jh) {
          const int rn = (r + 1 < OS) ? r + 1 : OS - 1;
          float xp1 = (float)jl * SC; float w1 = xp1 - (float)r;
          float xp2 = (float)jh * SC; float w2 = xp2 - (float)r;
          float v1 = cv[r] * (1.0f - w1) + cv[rn] * w1;
          float v2 = cv[r] * (1.0f - w2) + cv[rn] * w2;
          m = fmaxf(m, fmaxf(v1, v2));
        }
      }
      hsS[x] = m;
    }
  }
  __syncthreads();

  // phase C: parallel minmax_norm + obj_loc. wave0 -> wscore(x), wave1 -> hscore(y)
  if (wid < 2) {
    const float* s = (wid == 0) ? wsS : hsS;
    float v[7];
    float mn = 1e30f, mx = -1e30f;
#pragma unroll
    for (int q = 0; q < 7; ++q) {
      v[q] = s[lane + 64 * q];
      mn = fminf(mn, v[q]); mx = fmaxf(mx, v[q]);
    }
#pragma unroll
    for (int off = 32; off > 0; off >>= 1) {
      mn = fminf(mn, __shfl_down(mn, off));
      mx = fmaxf(mx, __shfl_down(mx, off));
    }
    mn = __shfl(mn, 0); mx = __shfl(mx, 0);
    float rng = mx - mn;
    float dnm = (mx != 0.0f) ? mx : 1.0f;
    int firstL = 1 << 30, lastL = -1;
#pragma unroll
    for (int q = 0; q < 7; ++q) {
      float nv = (rng > 0.0f) ? (v[q] - mn) / rng : v[q] / dnm;
      if (nv >= 0.5f) {
        int idx = lane + 64 * q;
        firstL = min(firstL, idx);
        lastL = max(lastL, idx);
      }
    }
#pragma unroll
    for (int off = 32; off > 0; off >>= 1) {
      firstL = min(firstL, __shfl_down(firstL, off));
      lastL = max(lastL, __shfl_down(lastL, off));
    }
    if (lane == 0) {
      int lo, hi;
      if (lastL >= 0) { lo = firstL; hi = lastL + 1; }
      else { lo = 56; hi = 392; }             // int(448*0.125), int(448*0.875)
      int need = 56 - (hi - lo); if (need < 0) need = 0;
      int pad = (need + 1) >> 1;
      lo = lo - pad; if (lo < 0) lo = 0;
      hi = hi + pad; if (hi > HW) hi = HW;
      if (wid == 0) { shb[2] = lo; shb[3] = hi; }  // x1,x2
      else          { shb[0] = lo; shb[1] = hi; }  // y1,y2
    }
  }
  __syncthreads();

  // phase D: fused bilinear crop-sample of the 42x42x3 conv input grid -> patchg[bt]
  const int y1 = shb[0], y2 = shb[1], x1 = shb[2], x2 = shb[3];
  const float y1f = (float)y1, x1f = (float)x1;
  const float sy = (float)(y2 - 1 - y1) / 447.0f;
  const float sx = (float)(x2 - 1 - x1) / 447.0f;
  const float* img = in + (size_t)b * 3 * HW * HW;
  for (int i = tid; i < PATCH; i += 1024) {
    int c = i / 1764, rem = i % 1764, r = rem / 42, cc = rem % 42;
    int yy = 32 * (r / 3) + (r % 3) - 1;   // crop-space row (conv pad -> -1)
    int xx = 32 * (cc / 3) + (cc % 3) - 1;
    float v = 0.0f;
    if (yy >= 0 && xx >= 0) {
      float ys = y1f + (float)yy * sy;
      float xs = x1f + (float)xx * sx;
      float y0 = floorf(ys); if (y0 < 0.0f) y0 = 0.0f; if (y0 > 447.0f) y0 = 447.0f;
      float x0 = floorf(xs); if (x0 < 0.0f) x0 = 0.0f; if (x0 > 447.0f) x0 = 447.0f;
      int y0i = (int)y0, x0i = (int)x0;
      int y1i = min(y0i + 1, HW - 1), x1i = min(x0i + 1, HW - 1);
      float wy = ys - y0, wx = xs - x0;
      const float* ic = img + (size_t)c * HW * HW;
      float a  = ic[y0i * HW + x0i], bb = ic[y0i * HW + x1i];
      float cc2 = ic[y1i * HW + x0i], d  = ic[y1i * HW + x1i];
      float top = a * (1.0f - wx) + bb * wx;
      float bot = cc2 * (1.0f - wx) + d * wx;
      v = top * (1.0f - wy) + bot * wy;
    }
    patchg[(size_t)bt * PATCH + i] = v;
  }
}

// ---------------- K4: local conv on pre-staged crop patches, row-split 14x.
// grid (5, 32, 14). Epilogue: f64 atomicAdd of the row partial into lfa[bt][f].
__global__ __launch_bounds__(256) void k4_conv_local(
    const float* __restrict__ patchg, // (32,5292)
    const float* __restrict__ fw,
    const float* __restrict__ fb,
    double* __restrict__ lfa)       // (32,1280) accumulator (zeroed by k3)
{
  __shared__ float patch[ROWPATCH];
  __shared__ float wlds[WLDS];
  const int bt = blockIdx.y, fc = blockIdx.x, oy = blockIdx.z, tid = threadIdx.x;
  for (int i = tid; i < WLDS; i += 256) wlds[i] = fw[fc * WLDS + i];
  for (int i = tid; i < ROWPATCH; i += 256) {
    int c = i / 126, rem = i % 126, rr = rem / 42, cc = rem % 42;
    patch[i] = patchg[(size_t)bt * PATCH + c * 1764 + (3 * oy + rr) * 42 + cc];
  }
  __syncthreads();
  const int f = fc * 256 + tid;
  float w[27];
#pragma unroll
  for (int k = 0; k < 27; ++k) w[k] = wlds[tid * 27 + k];
  const float bias = fb[f];
  double sum = 0.0;
#pragma unroll 7
  for (int ox = 0; ox < OS; ++ox) {
    float acc = bias;
#pragma unroll
    for (int c = 0; c < 3; ++c)
#pragma unroll
      for (int ky = 0; ky < 3; ++ky)
#pragma unroll
        for (int kx = 0; kx < 3; ++kx)
          acc += patch[c * 126 + ky * 42 + ox * 3 + kx] * w[c * 9 + ky * 3 + kx];
    acc = fminf(fmaxf(acc, 0.0f), 6.0f);
    sum += (double)acc;
  }
  atomicAdd(&lfa[(size_t)bt * NF + f], sum);
}

// ---------------- K5: ls = max over t of sigmoid(1x1 conv on lf). One wave per (b, cls).
// lf value reconstructed inline: (float)(lfa/196.0) — same expression as the old kcomb.
__global__ __launch_bounds__(64) void k5_ls(
    const double* __restrict__ lfa, // (32,1280)
    const float* __restrict__ cw,
    const float* __restrict__ cb,
    float* __restrict__ ls_out)     // d_out + 640
{
  const int cls = blockIdx.x, b = blockIdx.y, lane = threadIdx.x;
  const float* w = cw + (size_t)cls * NF;
  const double* l0 = lfa + (size_t)(b * TOPN + 0) * NF;
  const double* l1 = lfa + (size_t)(b * TOPN + 1) * NF;
  const double* l2 = lfa + (size_t)(b * TOPN + 2) * NF;
  const double* l3 = lfa + (size_t)(b * TOPN + 3) * NF;
  double a0 = 0.0, a1 = 0.0, a2 = 0.0, a3 = 0.0;
#pragma unroll
  for (int k = 0; k < NF / 64; ++k) {
    const int f = k * 64 + lane;
    const double wv = (double)w[f];
    a0 += wv * (double)(float)(l0[f] / 196.0);
    a1 += wv * (double)(float)(l1[f] / 196.0);
    a2 += wv * (double)(float)(l2[f] / 196.0);
    a3 += wv * (double)(float)(l3[f] / 196.0);
  }
  a0 = wave_reduce_f64(a0);
  a1 = wave_reduce_f64(a1);
  a2 = wave_reduce_f64(a2);
  a3 = wave_reduce_f64(a3);
  if (lane == 0) {
    const double bias = (double)cb[cls];
    float m = sigmoidf_((float)(a0 + bias));
    m = fmaxf(m, sigmoidf_((float)(a1 + bias)));
    m = fmaxf(m, sigmoidf_((float)(a2 + bias)));
    m = fmaxf(m, sigmoidf_((float)(a3 + bias)));
    ls_out[b * NC + cls] = m;
  }
}

extern "C" void kernel_launch(void* const* d_in, const int* in_sizes, int n_in,
                              void* d_out, int out_size, void* d_ws, size_t ws_size,
                              hipStream_t stream) {
  const float* in = (const float*)d_in[0];   // (8,3,448,448)
  const float* fw = (const float*)d_in[1];   // (1280,3,3,3)
  const float* fb = (const float*)d_in[2];   // (1280)
  const float* cw = (const float*)d_in[3];   // (80,1280,1,1)
  const float* cb = (const float*)d_in[4];   // (80)
  float* out = (float*)d_out;                // gs(640) ++ ls(640)

  // ws layout (f64 arrays first for alignment)
  double* gfp = (double*)d_ws;                            // 14*8*1280
  double* lfa = gfp + (size_t)OS * NB * NF;               // 32*1280
  float* ga = (float*)(lfa + (size_t)NB * TOPN * NF);     // 8*196*1280
  float* patchg = ga + (size_t)NB * NP * NF;              // 32*5292
  int* topi = (int*)(patchg + (size_t)NB * TOPN * PATCH); // 32

  k1_conv_global<<<dim3(5, NB, OS), 256, 0, stream>>>(in, fw, fb, ga, gfp);
  k2_gs_topk<<<NB, 1024, 0, stream>>>(gfp, cw, cb, out, topi);
  k3_cam_bounds_stage<<<NB * TOPN, 1024, 0, stream>>>(ga, cw, cb, topi, in, patchg, lfa);
  k4_conv_local<<<dim3(5, NB * TOPN, OS), 256, 0, stream>>>(patchg, fw, fb, lfa);
  k5_ls<<<dim3(NC, NB), 64, 0, stream>>>(lfa, cw, cb, out + 640);
}

// Round 10
// 162.058 us; speedup vs baseline: 1.0612x; 1.0612x over previous
//
#include <hip/hip_runtime.h>
#include <math.h>

// Problem constants
#define NB 8           // batch
#define TOPN 4
#define NC 80          // classes
#define NF 1280        // features
#define HW 448         // image H=W
#define OS 14          // conv out spatial
#define NP 196         // OS*OS
#define PATCH (3*42*42)   // full 42x42x3 crop sample grid
#define ROWPATCH (3*3*42) // one output-row's input grid: 3 ch x 3 rows x 42 cols
#define WLDS (256*27)     // per-chunk filter weights staged in LDS

__device__ __forceinline__ float sigmoidf_(float x) { return 1.0f / (1.0f + expf(-x)); }

__device__ __forceinline__ double wave_reduce_f64(double v) {
#pragma unroll
  for (int off = 32; off > 0; off >>= 1) v += __shfl_down(v, off);
  return v;
}

// ---------------- K1: global conv (stride 32, pad 1, clip 0..6), row-split 14x.
// grid (5, 8, 14): x = filter chunk (256 filters), y = batch, z = output row oy.
__global__ __launch_bounds__(256) void k1_conv_global(
    const float* __restrict__ in,   // (8,3,448,448)
    const float* __restrict__ fw,   // (1280,3,3,3) flat
    const float* __restrict__ fb,   // (1280)
    float* __restrict__ ga,         // (8,196,1280)
    double* __restrict__ gfp)       // (14,8,1280) per-row partial sums
{
  __shared__ float patch[ROWPATCH];   // [c][rr][cc] : c*126 + rr*42 + cc
  __shared__ float wlds[WLDS];
  const int b = blockIdx.y, fc = blockIdx.x, oy = blockIdx.z, tid = threadIdx.x;
  for (int i = tid; i < WLDS; i += 256) wlds[i] = fw[fc * WLDS + i];
  for (int i = tid; i < ROWPATCH; i += 256) {
    int c = i / 126, rem = i % 126, rr = rem / 42, cc = rem % 42;
    int row = 32 * oy + rr - 1;
    int col = 32 * (cc / 3) + (cc % 3) - 1;
    float v = 0.0f;
    if (row >= 0 && col >= 0)
      v = in[((b * 3 + c) * HW + row) * HW + col];
    patch[i] = v;
  }
  __syncthreads();
  const int f = fc * 256 + tid;
  float w[27];
#pragma unroll
  for (int k = 0; k < 27; ++k) w[k] = wlds[tid * 27 + k];
  const float bias = fb[f];
  double sum = 0.0;
#pragma unroll 7
  for (int ox = 0; ox < OS; ++ox) {
    float acc = bias;
#pragma unroll
    for (int c = 0; c < 3; ++c)
#pragma unroll
      for (int ky = 0; ky < 3; ++ky)
#pragma unroll
        for (int kx = 0; kx < 3; ++kx)
          acc += patch[c * 126 + ky * 42 + ox * 3 + kx] * w[c * 9 + ky * 3 + kx];
    acc = fminf(fmaxf(acc, 0.0f), 6.0f);
    ga[((size_t)b * NP + oy * OS + ox) * NF + f] = acc;
    sum += (double)acc;
  }
  gfp[((size_t)oy * NB + b) * NF + f] = sum;
}

// ---------------- K2: gs = sigmoid(1x1 conv on gf) + top-4, one 1024-thread block per batch.
__global__ __launch_bounds__(1024) void k2_gs_topk(
    const double* __restrict__ gfp, // (14,8,1280)
    const float* __restrict__ cw,   // (80,1280)
    const float* __restrict__ cb,   // (80)
    float* __restrict__ gs_out,     // d_out (8,80)
    int* __restrict__ topi)         // (8,4)
{
  __shared__ float gfs[NF];
  __shared__ float gsv[NC];
  const int b = blockIdx.x, tid = threadIdx.x;
  for (int i = tid; i < NF; i += 1024) {
    double s = 0.0;
#pragma unroll
    for (int z = 0; z < OS; ++z) s += gfp[((size_t)z * NB + b) * NF + i];
    gfs[i] = (float)(s / 196.0);
  }
  __syncthreads();
  const int wid = tid >> 6, lane = tid & 63;
  for (int j = 0; j < 5; ++j) {
    const int cls = wid * 5 + j;
    const float* w = cw + (size_t)cls * NF;
    double acc = 0.0;
#pragma unroll
    for (int k = 0; k < NF / 64; ++k) {
      int f = k * 64 + lane;
      acc += (double)w[f] * (double)gfs[f];
    }
    acc = wave_reduce_f64(acc);
    if (lane == 0) {
      float s = sigmoidf_((float)(acc + (double)cb[cls]));
      gsv[cls] = s;
      gs_out[b * NC + cls] = s;
    }
  }
  __syncthreads();
  if (wid == 0) {
    float v0 = gsv[lane];
    float v1 = (lane < NC - 64) ? gsv[64 + lane] : -1e30f;
    const int i0 = lane, i1 = 64 + lane;
#pragma unroll
    for (int t = 0; t < TOPN; ++t) {
      float bv; int bi;
      if (v1 > v0) { bv = v1; bi = i1; } else { bv = v0; bi = i0; }
#pragma unroll
      for (int off = 1; off < 64; off <<= 1) {
        float ov = __shfl_xor(bv, off);
        int oi = __shfl_xor(bi, off);
        if (ov > bv || (ov == bv && oi < bi)) { bv = ov; bi = oi; }
      }
      if (lane == 0) topi[b * TOPN + t] = bi;
      if (bi == i0) v0 = -1e30f;
      if (bi == i1) v1 = -1e30f;
    }
  }
}

// ---------------- K3a: cam dots — one wave per (bt, p); clsw staged in LDS per block.
// grid (49, 32), 256 threads (4 waves). High wave-parallelism (1568 blocks).
__global__ __launch_bounds__(256) void k3a_cam(
    const float* __restrict__ ga,   // (8,196,1280)
    const float* __restrict__ cw,
    const float* __restrict__ cb,
    const int* __restrict__ topi,
    float* __restrict__ camg)       // (32,196)
{
  __shared__ float clsw[NF];
  const int pc = blockIdx.x, bt = blockIdx.y;
  const int tid = threadIdx.x, wid = tid >> 6, lane = tid & 63;
  const int p = pc * 4 + wid;
  const int b = bt >> 2;
  const int cls = topi[bt];
  for (int i = tid; i < NF; i += 256) clsw[i] = cw[(size_t)cls * NF + i];
  __syncthreads();
  const float* g = ga + ((size_t)b * NP + p) * NF;
  double acc = 0.0;
#pragma unroll
  for (int k = 0; k < NF / 64; ++k) {
    const int f = k * 64 + lane;
    acc += (double)g[f] * (double)clsw[f];
  }
  acc = wave_reduce_f64(acc);
  if (lane == 0) camg[bt * NP + p] = sigmoidf_((float)(acc + (double)cb[cls]));
}

// ---------------- K3b: per bt: segment-max scores -> bounds -> fused bilinear crop-staging.
// Also zeroes lfa[bt] (k4's accumulator; k3b precedes k4 in stream order).
__global__ __launch_bounds__(256) void k3b_bounds_stage(
    const float* __restrict__ camg, // (32,196)
    const float* __restrict__ in,   // (8,3,448,448)
    float* __restrict__ patchg,     // (32,5292)
    double* __restrict__ lfa)       // (32,1280) accumulator, zeroed here
{
  __shared__ float cam[NP];
  __shared__ float wsS[HW];
  __shared__ float hsS[HW];
  __shared__ int jlo[OS], jhi[OS];
  __shared__ int shb[4];            // y1,y2,x1,x2
  const int bt = blockIdx.x, tid = threadIdx.x;
  const int wid = tid >> 6, lane = tid & 63;
  const float SC = 13.0f / 447.0f;

  if (tid < OS) { jlo[tid] = 1 << 30; jhi[tid] = -1; }
  for (int i = tid; i < NP; i += 256) cam[i] = camg[bt * NP + i];
  for (int i = tid; i < NF; i += 256) lfa[(size_t)bt * NF + i] = 0.0;
  __syncthreads();
  for (int j = tid; j < HW; j += 256) {
    float yp = (float)j * SC;
    int y0 = (int)floorf(yp); if (y0 > 13) y0 = 13;
    atomicMin(&jlo[y0], j);
    atomicMax(&jhi[y0], j);
  }
  __syncthreads();

  // phase B: per output column/row, piecewise-linear segment max (2 evals/segment)
  for (int x = tid; x < HW; x += 256) {
    float xp = (float)x * SC;
    int x0 = (int)floorf(xp); if (x0 > 13) x0 = 13;
    float wx = xp - (float)x0;
    int x1i = min(x0 + 1, 13);
    {
      float cv[OS];
#pragma unroll
      for (int r = 0; r < OS; ++r)
        cv[r] = cam[r * OS + x0] * (1.0f - wx) + cam[r * OS + x1i] * wx;
      float m = -1e30f;
#pragma unroll
      for (int r = 0; r < OS; ++r) {
        int jl = jlo[r], jh = jhi[r];
        if (jl <= jh) {
          const int rn = (r + 1 < OS) ? r + 1 : OS - 1;
          float yp1 = (float)jl * SC; float wy1 = yp1 - (float)r;
          float yp2 = (float)jh * SC; float wy2 = yp2 - (float)r;
          float v1 = cv[r] * (1.0f - wy1) + cv[rn] * wy1;
          float v2 = cv[r] * (1.0f - wy2) + cv[rn] * wy2;
          m = fmaxf(m, fmaxf(v1, v2));
        }
      }
      wsS[x] = m;
    }
    {
      float cv[OS];
#pragma unroll
      for (int c = 0; c < OS; ++c)
        cv[c] = cam[x0 * OS + c] * (1.0f - wx) + cam[x1i * OS + c] * wx;
      float m = -1e30f;
#pragma unroll
      for (int r = 0; r < OS; ++r) {
        int jl = jlo[r], jh = jhi[r];
        if (jl <= jh) {
          const int rn = (r + 1 < OS) ? r + 1 : OS - 1;
          float xp1 = (float)jl * SC; float w1 = xp1 - (float)r;
          float xp2 = (float)jh * SC; float w2 = xp2 - (float)r;
          float v1 = cv[r] * (1.0f - w1) + cv[rn] * w1;
          float v2 = cv[r] * (1.0f - w2) + cv[rn] * w2;
          m = fmaxf(m, fmaxf(v1, v2));
        }
      }
      hsS[x] = m;
    }
  }
  __syncthreads();

  // phase C: parallel minmax_norm + obj_loc. wave0 -> wscore(x), wave1 -> hscore(y)
  if (wid < 2) {
    const float* s = (wid == 0) ? wsS : hsS;
    float v[7];
    float mn = 1e30f, mx = -1e30f;
#pragma unroll
    for (int q = 0; q < 7; ++q) {
      v[q] = s[lane + 64 * q];
      mn = fminf(mn, v[q]); mx = fmaxf(mx, v[q]);
    }
#pragma unroll
    for (int off = 32; off > 0; off >>= 1) {
      mn = fminf(mn, __shfl_down(mn, off));
      mx = fmaxf(mx, __shfl_down(mx, off));
    }
    mn = __shfl(mn, 0); mx = __shfl(mx, 0);
    float rng = mx - mn;
    float dnm = (mx != 0.0f) ? mx : 1.0f;
    int firstL = 1 << 30, lastL = -1;
#pragma unroll
    for (int q = 0; q < 7; ++q) {
      float nv = (rng > 0.0f) ? (v[q] - mn) / rng : v[q] / dnm;
      if (nv >= 0.5f) {
        int idx = lane + 64 * q;
        firstL = min(firstL, idx);
        lastL = max(lastL, idx);
      }
    }
#pragma unroll
    for (int off = 32; off > 0; off >>= 1) {
      firstL = min(firstL, __shfl_down(firstL, off));
      lastL = max(lastL, __shfl_down(lastL, off));
    }
    if (lane == 0) {
      int lo, hi;
      if (lastL >= 0) { lo = firstL; hi = lastL + 1; }
      else { lo = 56; hi = 392; }             // int(448*0.125), int(448*0.875)
      int need = 56 - (hi - lo); if (need < 0) need = 0;
      int pad = (need + 1) >> 1;
      lo = lo - pad; if (lo < 0) lo = 0;
      hi = hi + pad; if (hi > HW) hi = HW;
      if (wid == 0) { shb[2] = lo; shb[3] = hi; }  // x1,x2
      else          { shb[0] = lo; shb[1] = hi; }  // y1,y2
    }
  }
  __syncthreads();

  // phase D: fused bilinear crop-sample of the 42x42x3 conv input grid -> patchg[bt]
  const int b = bt >> 2;
  const int y1 = shb[0], y2 = shb[1], x1 = shb[2], x2 = shb[3];
  const float y1f = (float)y1, x1f = (float)x1;
  const float sy = (float)(y2 - 1 - y1) / 447.0f;
  const float sx = (float)(x2 - 1 - x1) / 447.0f;
  const float* img = in + (size_t)b * 3 * HW * HW;
  for (int i = tid; i < PATCH; i += 256) {
    int c = i / 1764, rem = i % 1764, r = rem / 42, cc = rem % 42;
    int yy = 32 * (r / 3) + (r % 3) - 1;   // crop-space row (conv pad -> -1)
    int xx = 32 * (cc / 3) + (cc % 3) - 1;
    float v = 0.0f;
    if (yy >= 0 && xx >= 0) {
      float ys = y1f + (float)yy * sy;
      float xs = x1f + (float)xx * sx;
      float y0 = floorf(ys); if (y0 < 0.0f) y0 = 0.0f; if (y0 > 447.0f) y0 = 447.0f;
      float x0 = floorf(xs); if (x0 < 0.0f) x0 = 0.0f; if (x0 > 447.0f) x0 = 447.0f;
      int y0i = (int)y0, x0i = (int)x0;
      int y1i = min(y0i + 1, HW - 1), x1i = min(x0i + 1, HW - 1);
      float wy = ys - y0, wx = xs - x0;
      const float* ic = img + (size_t)c * HW * HW;
      float a  = ic[y0i * HW + x0i], bb = ic[y0i * HW + x1i];
      float cc2 = ic[y1i * HW + x0i], d  = ic[y1i * HW + x1i];
      float top = a * (1.0f - wx) + bb * wx;
      float bot = cc2 * (1.0f - wx) + d * wx;
      v = top * (1.0f - wy) + bot * wy;
    }
    patchg[(size_t)bt * PATCH + i] = v;
  }
}

// ---------------- K4: local conv on pre-staged crop patches, row-split 14x.
// grid (5, 32, 14). Epilogue: f64 atomicAdd of the row partial into lfa[bt][f].
__global__ __launch_bounds__(256) void k4_conv_local(
    const float* __restrict__ patchg, // (32,5292)
    const float* __restrict__ fw,
    const float* __restrict__ fb,
    double* __restrict__ lfa)       // (32,1280) accumulator (zeroed by k3b)
{
  __shared__ float patch[ROWPATCH];
  __shared__ float wlds[WLDS];
  const int bt = blockIdx.y, fc = blockIdx.x, oy = blockIdx.z, tid = threadIdx.x;
  for (int i = tid; i < WLDS; i += 256) wlds[i] = fw[fc * WLDS + i];
  for (int i = tid; i < ROWPATCH; i += 256) {
    int c = i / 126, rem = i % 126, rr = rem / 42, cc = rem % 42;
    patch[i] = patchg[(size_t)bt * PATCH + c * 1764 + (3 * oy + rr) * 42 + cc];
  }
  __syncthreads();
  const int f = fc * 256 + tid;
  float w[27];
#pragma unroll
  for (int k = 0; k < 27; ++k) w[k] = wlds[tid * 27 + k];
  const float bias = fb[f];
  double sum = 0.0;
#pragma unroll 7
  for (int ox = 0; ox < OS; ++ox) {
    float acc = bias;
#pragma unroll
    for (int c = 0; c < 3; ++c)
#pragma unroll
      for (int ky = 0; ky < 3; ++ky)
#pragma unroll
        for (int kx = 0; kx < 3; ++kx)
          acc += patch[c * 126 + ky * 42 + ox * 3 + kx] * w[c * 9 + ky * 3 + kx];
    acc = fminf(fmaxf(acc, 0.0f), 6.0f);
    sum += (double)acc;
  }
  atomicAdd(&lfa[(size_t)bt * NF + f], sum);
}

// ---------------- K5: ls = max over t of sigmoid(1x1 conv on lf). One wave per (b, cls).
// lf value reconstructed inline: (float)(lfa/196.0) — same expression kcomb used.
__global__ __launch_bounds__(64) void k5_ls(
    const double* __restrict__ lfa, // (32,1280)
    const float* __restrict__ cw,
    const float* __restrict__ cb,
    float* __restrict__ ls_out)     // d_out + 640
{
  const int cls = blockIdx.x, b = blockIdx.y, lane = threadIdx.x;
  const float* w = cw + (size_t)cls * NF;
  const double* l0 = lfa + (size_t)(b * TOPN + 0) * NF;
  const double* l1 = lfa + (size_t)(b * TOPN + 1) * NF;
  const double* l2 = lfa + (size_t)(b * TOPN + 2) * NF;
  const double* l3 = lfa + (size_t)(b * TOPN + 3) * NF;
  double a0 = 0.0, a1 = 0.0, a2 = 0.0, a3 = 0.0;
#pragma unroll
  for (int k = 0; k < NF / 64; ++k) {
    const int f = k * 64 + lane;
    const double wv = (double)w[f];
    a0 += wv * (double)(float)(l0[f] / 196.0);
    a1 += wv * (double)(float)(l1[f] / 196.0);
    a2 += wv * (double)(float)(l2[f] / 196.0);
    a3 += wv * (double)(float)(l3[f] / 196.0);
  }
  a0 = wave_reduce_f64(a0);
  a1 = wave_reduce_f64(a1);
  a2 = wave_reduce_f64(a2);
  a3 = wave_reduce_f64(a3);
  if (lane == 0) {
    const double bias = (double)cb[cls];
    float m = sigmoidf_((float)(a0 + bias));
    m = fmaxf(m, sigmoidf_((float)(a1 + bias)));
    m = fmaxf(m, sigmoidf_((float)(a2 + bias)));
    m = fmaxf(m, sigmoidf_((float)(a3 + bias)));
    ls_out[b * NC + cls] = m;
  }
}

extern "C" void kernel_launch(void* const* d_in, const int* in_sizes, int n_in,
                              void* d_out, int out_size, void* d_ws, size_t ws_size,
                              hipStream_t stream) {
  const float* in = (const float*)d_in[0];   // (8,3,448,448)
  const float* fw = (const float*)d_in[1];   // (1280,3,3,3)
  const float* fb = (const float*)d_in[2];   // (1280)
  const float* cw = (const float*)d_in[3];   // (80,1280,1,1)
  const float* cb = (const float*)d_in[4];   // (80)
  float* out = (float*)d_out;                // gs(640) ++ ls(640)

  // ws layout (f64 arrays first for alignment)
  double* gfp = (double*)d_ws;                            // 14*8*1280
  double* lfa = gfp + (size_t)OS * NB * NF;               // 32*1280
  float* ga = (float*)(lfa + (size_t)NB * TOPN * NF);     // 8*196*1280
  float* patchg = ga + (size_t)NB * NP * NF;              // 32*5292
  float* camg = patchg + (size_t)NB * TOPN * PATCH;       // 32*196
  int* topi = (int*)(camg + NB * TOPN * NP);              // 32

  k1_conv_global<<<dim3(5, NB, OS), 256, 0, stream>>>(in, fw, fb, ga, gfp);
  k2_gs_topk<<<NB, 1024, 0, stream>>>(gfp, cw, cb, out, topi);
  k3a_cam<<<dim3(NP / 4, NB * TOPN), 256, 0, stream>>>(ga, cw, cb, topi, camg);
  k3b_bounds_stage<<<NB * TOPN, 256, 0, stream>>>(camg, in, patchg, lfa);
  k4_conv_local<<<dim3(5, NB * TOPN, OS), 256, 0, stream>>>(patchg, fw, fb, lfa);
  k5_ls<<<dim3(NC, NB), 64, 0, stream>>>(lfa, cw, cb, out + 640);
}

// Round 11
// 144.966 us; speedup vs baseline: 1.1864x; 1.1179x over previous
//
#include <hip/hip_runtime.h>
#include <math.h>

// Problem constants
#define NB 8           // batch
#define TOPN 4
#define NC 80          // classes
#define NF 1280        // features
#define HW 448         // image H=W
#define OS 14          // conv out spatial
#define NP 196         // OS*OS
#define PATCH (3*42*42)   // full 42x42x3 crop sample grid
#define ROWPATCH (3*3*42) // one output-row's input grid: 3 ch x 3 rows x 42 cols
#define WLDS (256*27)     // per-chunk filter weights staged in LDS

__device__ __forceinline__ float sigmoidf_(float x) { return 1.0f / (1.0f + expf(-x)); }

__device__ __forceinline__ double wave_reduce_f64(double v) {
#pragma unroll
  for (int off = 32; off > 0; off >>= 1) v += __shfl_down(v, off);
  return v;
}

// ---------------- K1: global conv (stride 32, pad 1, clip 0..6), row-split 14x.
// grid (5, 8, 14): x = filter chunk (256 filters), y = batch, z = output row oy.
__global__ __launch_bounds__(256) void k1_conv_global(
    const float* __restrict__ in,   // (8,3,448,448)
    const float* __restrict__ fw,   // (1280,3,3,3) flat
    const float* __restrict__ fb,   // (1280)
    float* __restrict__ ga,         // (8,196,1280)
    double* __restrict__ gfp)       // (14,8,1280) per-row partial sums
{
  __shared__ float patch[ROWPATCH];   // [c][rr][cc] : c*126 + rr*42 + cc
  __shared__ float wlds[WLDS];
  const int b = blockIdx.y, fc = blockIdx.x, oy = blockIdx.z, tid = threadIdx.x;
  for (int i = tid; i < WLDS; i += 256) wlds[i] = fw[fc * WLDS + i];
  for (int i = tid; i < ROWPATCH; i += 256) {
    int c = i / 126, rem = i % 126, rr = rem / 42, cc = rem % 42;
    int row = 32 * oy + rr - 1;
    int col = 32 * (cc / 3) + (cc % 3) - 1;
    float v = 0.0f;
    if (row >= 0 && col >= 0)
      v = in[((b * 3 + c) * HW + row) * HW + col];
    patch[i] = v;
  }
  __syncthreads();
  const int f = fc * 256 + tid;
  float w[27];
#pragma unroll
  for (int k = 0; k < 27; ++k) w[k] = wlds[tid * 27 + k];
  const float bias = fb[f];
  double sum = 0.0;
#pragma unroll 7
  for (int ox = 0; ox < OS; ++ox) {
    float acc = bias;
#pragma unroll
    for (int c = 0; c < 3; ++c)
#pragma unroll
      for (int ky = 0; ky < 3; ++ky)
#pragma unroll
        for (int kx = 0; kx < 3; ++kx)
          acc += patch[c * 126 + ky * 42 + ox * 3 + kx] * w[c * 9 + ky * 3 + kx];
    acc = fminf(fmaxf(acc, 0.0f), 6.0f);
    ga[((size_t)b * NP + oy * OS + ox) * NF + f] = acc;
    sum += (double)acc;
  }
  gfp[((size_t)oy * NB + b) * NF + f] = sum;
}

// ---------------- K2: gs = sigmoid(1x1 conv on gf) + top-4, one 1024-thread block per batch.
__global__ __launch_bounds__(1024) void k2_gs_topk(
    const double* __restrict__ gfp, // (14,8,1280)
    const float* __restrict__ cw,   // (80,1280)
    const float* __restrict__ cb,   // (80)
    float* __restrict__ gs_out,     // d_out (8,80)
    int* __restrict__ topi)         // (8,4)
{
  __shared__ float gfs[NF];
  __shared__ float gsv[NC];
  const int b = blockIdx.x, tid = threadIdx.x;
  for (int i = tid; i < NF; i += 1024) {
    double s = 0.0;
#pragma unroll
    for (int z = 0; z < OS; ++z) s += gfp[((size_t)z * NB + b) * NF + i];
    gfs[i] = (float)(s / 196.0);
  }
  __syncthreads();
  const int wid = tid >> 6, lane = tid & 63;
  for (int j = 0; j < 5; ++j) {
    const int cls = wid * 5 + j;
    const float* w = cw + (size_t)cls * NF;
    double acc = 0.0;
#pragma unroll
    for (int k = 0; k < NF / 64; ++k) {
      int f = k * 64 + lane;
      acc += (double)w[f] * (double)gfs[f];
    }
    acc = wave_reduce_f64(acc);
    if (lane == 0) {
      float s = sigmoidf_((float)(acc + (double)cb[cls]));
      gsv[cls] = s;
      gs_out[b * NC + cls] = s;
    }
  }
  __syncthreads();
  if (wid == 0) {
    float v0 = gsv[lane];
    float v1 = (lane < NC - 64) ? gsv[64 + lane] : -1e30f;
    const int i0 = lane, i1 = 64 + lane;
#pragma unroll
    for (int t = 0; t < TOPN; ++t) {
      float bv; int bi;
      if (v1 > v0) { bv = v1; bi = i1; } else { bv = v0; bi = i0; }
#pragma unroll
      for (int off = 1; off < 64; off <<= 1) {
        float ov = __shfl_xor(bv, off);
        int oi = __shfl_xor(bi, off);
        if (ov > bv || (ov == bv && oi < bi)) { bv = ov; bi = oi; }
      }
      if (lane == 0) topi[b * TOPN + t] = bi;
      if (bi == i0) v0 = -1e30f;
      if (bi == i1) v1 = -1e30f;
    }
  }
}

// ---------------- K3a: cam dots — one wave per (bt, p); clsw staged in LDS per block.
// grid (49, 32), 256 threads (4 waves). High wave-parallelism (1568 blocks).
__global__ __launch_bounds__(256) void k3a_cam(
    const float* __restrict__ ga,   // (8,196,1280)
    const float* __restrict__ cw,
    const float* __restrict__ cb,
    const int* __restrict__ topi,
    float* __restrict__ camg)       // (32,196)
{
  __shared__ float clsw[NF];
  const int pc = blockIdx.x, bt = blockIdx.y;
  const int tid = threadIdx.x, wid = tid >> 6, lane = tid & 63;
  const int p = pc * 4 + wid;
  const int b = bt >> 2;
  const int cls = topi[bt];
  for (int i = tid; i < NF; i += 256) clsw[i] = cw[(size_t)cls * NF + i];
  __syncthreads();
  const float* g = ga + ((size_t)b * NP + p) * NF;
  double acc = 0.0;
#pragma unroll
  for (int k = 0; k < NF / 64; ++k) {
    const int f = k * 64 + lane;
    acc += (double)g[f] * (double)clsw[f];
  }
  acc = wave_reduce_f64(acc);
  if (lane == 0) camg[bt * NP + p] = sigmoidf_((float)(acc + (double)cb[cls]));
}

// ---------------- K3b: per bt: segment-max scores -> bounds -> fused bilinear crop-staging.
__global__ __launch_bounds__(256) void k3b_bounds_stage(
    const float* __restrict__ camg, // (32,196)
    const float* __restrict__ in,   // (8,3,448,448)
    float* __restrict__ patchg)     // (32,5292)
{
  __shared__ float cam[NP];
  __shared__ float wsS[HW];
  __shared__ float hsS[HW];
  __shared__ int jlo[OS], jhi[OS];
  __shared__ int shb[4];            // y1,y2,x1,x2
  const int bt = blockIdx.x, tid = threadIdx.x;
  const int wid = tid >> 6, lane = tid & 63;
  const float SC = 13.0f / 447.0f;

  if (tid < OS) { jlo[tid] = 1 << 30; jhi[tid] = -1; }
  for (int i = tid; i < NP; i += 256) cam[i] = camg[bt * NP + i];
  __syncthreads();
  for (int j = tid; j < HW; j += 256) {
    float yp = (float)j * SC;
    int y0 = (int)floorf(yp); if (y0 > 13) y0 = 13;
    atomicMin(&jlo[y0], j);
    atomicMax(&jhi[y0], j);
  }
  __syncthreads();

  // phase B: per output column/row, piecewise-linear segment max (2 evals/segment)
  for (int x = tid; x < HW; x += 256) {
    float xp = (float)x * SC;
    int x0 = (int)floorf(xp); if (x0 > 13) x0 = 13;
    float wx = xp - (float)x0;
    int x1i = min(x0 + 1, 13);
    {
      float cv[OS];
#pragma unroll
      for (int r = 0; r < OS; ++r)
        cv[r] = cam[r * OS + x0] * (1.0f - wx) + cam[r * OS + x1i] * wx;
      float m = -1e30f;
#pragma unroll
      for (int r = 0; r < OS; ++r) {
        int jl = jlo[r], jh = jhi[r];
        if (jl <= jh) {
          const int rn = (r + 1 < OS) ? r + 1 : OS - 1;
          float yp1 = (float)jl * SC; float wy1 = yp1 - (float)r;
          float yp2 = (float)jh * SC; float wy2 = yp2 - (float)r;
          float v1 = cv[r] * (1.0f - wy1) + cv[rn] * wy1;
          float v2 = cv[r] * (1.0f - wy2) + cv[rn] * wy2;
          m = fmaxf(m, fmaxf(v1, v2));
        }
      }
      wsS[x] = m;
    }
    {
      float cv[OS];
#pragma unroll
      for (int c = 0; c < OS; ++c)
        cv[c] = cam[x0 * OS + c] * (1.0f - wx) + cam[x1i * OS + c] * wx;
      float m = -1e30f;
#pragma unroll
      for (int r = 0; r < OS; ++r) {
        int jl = jlo[r], jh = jhi[r];
        if (jl <= jh) {
          const int rn = (r + 1 < OS) ? r + 1 : OS - 1;
          float xp1 = (float)jl * SC; float w1 = xp1 - (float)r;
          float xp2 = (float)jh * SC; float w2 = xp2 - (float)r;
          float v1 = cv[r] * (1.0f - w1) + cv[rn] * w1;
          float v2 = cv[r] * (1.0f - w2) + cv[rn] * w2;
          m = fmaxf(m, fmaxf(v1, v2));
        }
      }
      hsS[x] = m;
    }
  }
  __syncthreads();

  // phase C: parallel minmax_norm + obj_loc. wave0 -> wscore(x), wave1 -> hscore(y)
  if (wid < 2) {
    const float* s = (wid == 0) ? wsS : hsS;
    float v[7];
    float mn = 1e30f, mx = -1e30f;
#pragma unroll
    for (int q = 0; q < 7; ++q) {
      v[q] = s[lane + 64 * q];
      mn = fminf(mn, v[q]); mx = fmaxf(mx, v[q]);
    }
#pragma unroll
    for (int off = 32; off > 0; off >>= 1) {
      mn = fminf(mn, __shfl_down(mn, off));
      mx = fmaxf(mx, __shfl_down(mx, off));
    }
    mn = __shfl(mn, 0); mx = __shfl(mx, 0);
    float rng = mx - mn;
    float dnm = (mx != 0.0f) ? mx : 1.0f;
    int firstL = 1 << 30, lastL = -1;
#pragma unroll
    for (int q = 0; q < 7; ++q) {
      float nv = (rng > 0.0f) ? (v[q] - mn) / rng : v[q] / dnm;
      if (nv >= 0.5f) {
        int idx = lane + 64 * q;
        firstL = min(firstL, idx);
        lastL = max(lastL, idx);
      }
    }
#pragma unroll
    for (int off = 32; off > 0; off >>= 1) {
      firstL = min(firstL, __shfl_down(firstL, off));
      lastL = max(lastL, __shfl_down(lastL, off));
    }
    if (lane == 0) {
      int lo, hi;
      if (lastL >= 0) { lo = firstL; hi = lastL + 1; }
      else { lo = 56; hi = 392; }             // int(448*0.125), int(448*0.875)
      int need = 56 - (hi - lo); if (need < 0) need = 0;
      int pad = (need + 1) >> 1;
      lo = lo - pad; if (lo < 0) lo = 0;
      hi = hi + pad; if (hi > HW) hi = HW;
      if (wid == 0) { shb[2] = lo; shb[3] = hi; }  // x1,x2
      else          { shb[0] = lo; shb[1] = hi; }  // y1,y2
    }
  }
  __syncthreads();

  // phase D: fused bilinear crop-sample of the 42x42x3 conv input grid -> patchg[bt]
  const int b = bt >> 2;
  const int y1 = shb[0], y2 = shb[1], x1 = shb[2], x2 = shb[3];
  const float y1f = (float)y1, x1f = (float)x1;
  const float sy = (float)(y2 - 1 - y1) / 447.0f;
  const float sx = (float)(x2 - 1 - x1) / 447.0f;
  const float* img = in + (size_t)b * 3 * HW * HW;
  for (int i = tid; i < PATCH; i += 256) {
    int c = i / 1764, rem = i % 1764, r = rem / 42, cc = rem % 42;
    int yy = 32 * (r / 3) + (r % 3) - 1;   // crop-space row (conv pad -> -1)
    int xx = 32 * (cc / 3) + (cc % 3) - 1;
    float v = 0.0f;
    if (yy >= 0 && xx >= 0) {
      float ys = y1f + (float)yy * sy;
      float xs = x1f + (float)xx * sx;
      float y0 = floorf(ys); if (y0 < 0.0f) y0 = 0.0f; if (y0 > 447.0f) y0 = 447.0f;
      float x0 = floorf(xs); if (x0 < 0.0f) x0 = 0.0f; if (x0 > 447.0f) x0 = 447.0f;
      int y0i = (int)y0, x0i = (int)x0;
      int y1i = min(y0i + 1, HW - 1), x1i = min(x0i + 1, HW - 1);
      float wy = ys - y0, wx = xs - x0;
      const float* ic = img + (size_t)c * HW * HW;
      float a  = ic[y0i * HW + x0i], bb = ic[y0i * HW + x1i];
      float cc2 = ic[y1i * HW + x0i], d  = ic[y1i * HW + x1i];
      float top = a * (1.0f - wx) + bb * wx;
      float bot = cc2 * (1.0f - wx) + d * wx;
      v = top * (1.0f - wy) + bot * wy;
    }
    patchg[(size_t)bt * PATCH + i] = v;
  }
}

// ---------------- K4: local conv on pre-staged crop patches, row-split 14x.
// grid (5, 32, 14). Stages 378 patch floats + 6912 weights coalesced in LDS.
__global__ __launch_bounds__(256) void k4_conv_local(
    const float* __restrict__ patchg, // (32,5292)
    const float* __restrict__ fw,
    const float* __restrict__ fb,
    double* __restrict__ lfp)       // (14,32,1280) per-row partial sums
{
  __shared__ float patch[ROWPATCH];
  __shared__ float wlds[WLDS];
  const int bt = blockIdx.y, fc = blockIdx.x, oy = blockIdx.z, tid = threadIdx.x;
  for (int i = tid; i < WLDS; i += 256) wlds[i] = fw[fc * WLDS + i];
  for (int i = tid; i < ROWPATCH; i += 256) {
    int c = i / 126, rem = i % 126, rr = rem / 42, cc = rem % 42;
    patch[i] = patchg[(size_t)bt * PATCH + c * 1764 + (3 * oy + rr) * 42 + cc];
  }
  __syncthreads();
  const int f = fc * 256 + tid;
  float w[27];
#pragma unroll
  for (int k = 0; k < 27; ++k) w[k] = wlds[tid * 27 + k];
  const float bias = fb[f];
  double sum = 0.0;
#pragma unroll 7
  for (int ox = 0; ox < OS; ++ox) {
    float acc = bias;
#pragma unroll
    for (int c = 0; c < 3; ++c)
#pragma unroll
      for (int ky = 0; ky < 3; ++ky)
#pragma unroll
        for (int kx = 0; kx < 3; ++kx)
          acc += patch[c * 126 + ky * 42 + ox * 3 + kx] * w[c * 9 + ky * 3 + kx];
    acc = fminf(fmaxf(acc, 0.0f), 6.0f);
    sum += (double)acc;
  }
  lfp[((size_t)oy * (NB * TOPN) + bt) * NF + f] = sum;
}

// ---------------- Kcomb: lf32[bt][f] = (float)(sum_z lfp[z][bt][f] / 196.0)
__global__ __launch_bounds__(256) void kcomb_lf(
    const double* __restrict__ lfp, // (14,32,1280)
    float* __restrict__ lf32)       // (32,1280)
{
  const int j = blockIdx.x * 256 + threadIdx.x;   // 0 .. 40959
  double s = 0.0;
#pragma unroll
  for (int z = 0; z < OS; ++z) s += lfp[(size_t)z * 40960 + j];
  lf32[j] = (float)(s / 196.0);
}

// ---------------- K5: ls = max over t of sigmoid(1x1 conv on lf32). One wave per (b, cls).
__global__ __launch_bounds__(64) void k5_ls(
    const float* __restrict__ lf32, // (32,1280)
    const float* __restrict__ cw,
    const float* __restrict__ cb,
    float* __restrict__ ls_out)     // d_out + 640
{
  const int cls = blockIdx.x, b = blockIdx.y, lane = threadIdx.x;
  const float* w = cw + (size_t)cls * NF;
  const float* l0 = lf32 + (size_t)(b * TOPN + 0) * NF;
  const float* l1 = lf32 + (size_t)(b * TOPN + 1) * NF;
  const float* l2 = lf32 + (size_t)(b * TOPN + 2) * NF;
  const float* l3 = lf32 + (size_t)(b * TOPN + 3) * NF;
  double a0 = 0.0, a1 = 0.0, a2 = 0.0, a3 = 0.0;
#pragma unroll
  for (int k = 0; k < NF / 64; ++k) {
    const int f = k * 64 + lane;
    const double wv = (double)w[f];
    a0 += wv * (double)l0[f];
    a1 += wv * (double)l1[f];
    a2 += wv * (double)l2[f];
    a3 += wv * (double)l3[f];
  }
  a0 = wave_reduce_f64(a0);
  a1 = wave_reduce_f64(a1);
  a2 = wave_reduce_f64(a2);
  a3 = wave_reduce_f64(a3);
  if (lane == 0) {
    const double bias = (double)cb[cls];
    float m = sigmoidf_((float)(a0 + bias));
    m = fmaxf(m, sigmoidf_((float)(a1 + bias)));
    m = fmaxf(m, sigmoidf_((float)(a2 + bias)));
    m = fmaxf(m, sigmoidf_((float)(a3 + bias)));
    ls_out[b * NC + cls] = m;
  }
}

extern "C" void kernel_launch(void* const* d_in, const int* in_sizes, int n_in,
                              void* d_out, int out_size, void* d_ws, size_t ws_size,
                              hipStream_t stream) {
  const float* in = (const float*)d_in[0];   // (8,3,448,448)
  const float* fw = (const float*)d_in[1];   // (1280,3,3,3)
  const float* fb = (const float*)d_in[2];   // (1280)
  const float* cw = (const float*)d_in[3];   // (80,1280,1,1)
  const float* cb = (const float*)d_in[4];   // (80)
  float* out = (float*)d_out;                // gs(640) ++ ls(640)

  // ws layout (f64 arrays first for alignment): ~15 MB total
  double* gfp = (double*)d_ws;                            // 14*8*1280
  double* lfp = gfp + (size_t)OS * NB * NF;               // 14*32*1280
  float* ga = (float*)(lfp + (size_t)OS * NB * TOPN * NF);// 8*196*1280
  float* lf32 = ga + (size_t)NB * NP * NF;                // 32*1280
  float* patchg = lf32 + (size_t)NB * TOPN * NF;          // 32*5292
  float* camg = patchg + (size_t)NB * TOPN * PATCH;       // 32*196
  int* topi = (int*)(camg + NB * TOPN * NP);              // 32

  k1_conv_global<<<dim3(5, NB, OS), 256, 0, stream>>>(in, fw, fb, ga, gfp);
  k2_gs_topk<<<NB, 1024, 0, stream>>>(gfp, cw, cb, out, topi);
  k3a_cam<<<dim3(NP / 4, NB * TOPN), 256, 0, stream>>>(ga, cw, cb, topi, camg);
  k3b_bounds_stage<<<NB * TOPN, 256, 0, stream>>>(camg, in, patchg);
  k4_conv_local<<<dim3(5, NB * TOPN, OS), 256, 0, stream>>>(patchg, fw, fb, lfp);
  kcomb_lf<<<NB * TOPN * NF / 256, 256, 0, stream>>>(lfp, lf32);
  k5_ls<<<dim3(NC, NB), 64, 0, stream>>>(lf32, cw, cb, out + 640);
}